// Round 8
// baseline (66.888 us; speedup 1.0000x reference)
//
#include <hip/hip_runtime.h>
#include <hip/hip_bf16.h>
#include <type_traits>

// SimCLR loss, MI355X. N=8192 rows, D=128, T=0.5.
// normalize(f32->bf16) -> SYMMETRIC sim-GEMM + sum(exp(2*dot)) over the
// 128-row-group upper triangle, blocks = (I, chunk of 2 J-groups) -> NT=4
// pipelined 64-col LDS tiles (R5-depth) at R7 granularity. 1024 full chunks
// (exactly 4/CU) dispatch first; 32 half-chunks trail as tail-filler.
// Fixed-max logsumexp (|sim|<=2) -> no online max.

#define BATCH 4096
#define N_TOT 8192
#define DIM 128
#define GRP 128                           // rows per group
#define NGRP 64
#define TILE_C 64                         // cols per LDS B-tile (16 KB)
#define NBLK 1056                         // 1024 full + 32 half chunks
#define NSLOT 96                          // rowsum slots 0..31, colsum slots 32+I

// exp(2d) == exp2(d * 2/ln2)
#define C_LOG2E2 2.8853900817779268f

using bf16x8 = __attribute__((ext_vector_type(8))) __bf16;
using f32x4  = __attribute__((ext_vector_type(4))) float;

typedef __attribute__((address_space(1))) const void cg_void;
typedef __attribute__((address_space(3))) void lds_void;
__device__ __forceinline__ void gll16(const void* g, void* l) {
    __builtin_amdgcn_global_load_lds((cg_void*)g, (lds_void*)l, 16, 0, 0);
}

// ---------------- kernel 1: normalize rows, write bf16 ----------------
__global__ __launch_bounds__(256) void k_normalize(const float* __restrict__ zi,
                                                   const float* __restrict__ zj,
                                                   __hip_bfloat16* __restrict__ zn) {
    int row  = blockIdx.x * 4 + (threadIdx.x >> 6);
    int lane = threadIdx.x & 63;
    const float* src = (row < BATCH) ? (zi + (size_t)row * DIM)
                                     : (zj + (size_t)(row - BATCH) * DIM);
    float2 v = ((const float2*)src)[lane];
    float ss = v.x * v.x + v.y * v.y;
    #pragma unroll
    for (int m = 1; m < 64; m <<= 1) ss += __shfl_xor(ss, m);
    float inv = 1.0f / fmaxf(sqrtf(ss), 1e-8f);
    __hip_bfloat162 o;
    o.x = __float2bfloat16(v.x * inv);
    o.y = __float2bfloat16(v.y * inv);
    ((__hip_bfloat162*)(zn + (size_t)row * DIM))[lane] = o;
}

// ---------------- kernel 2: symmetric sim GEMM + exp row/col sums ----------------
// Block (I, chunk c): A = 128 rows of group I in regs (32/wave), B = cols of
// groups J0=I+2c and J0+1 (full chunk) or J0=63 only (half chunk), staged as
// 64-col XOR-swizzled LDS tiles, ping-pong, stage(t+1) under compute(t).
// Rowsum of rows(I) -> slot c; colsum of rows(Jg) -> slot 32+I. Each
// (slot,row) has exactly one writer -> deterministic, no atomics.
__global__ __launch_bounds__(256, 4) void k_main(const __hip_bfloat16* __restrict__ zn_,
                                                 float* __restrict__ S_contrib) {
    __shared__ __align__(16) char Bs[2][TILE_C * 256];       // 32 KB
    __shared__ float colred[4][256];                         // 4 KB

    const int tid  = threadIdx.x;
    const int lane = tid & 63;
    const int wv   = tid >> 6;                        // 0..3
    const int l15  = lane & 15;
    const int lb   = lane >> 4;                       // 0..3

    // decode block -> (I, c): full chunks first (F(m) = m*(64-m) per even/odd pair)
    int I, c, ngrp2;
    if (blockIdx.x < 1024) {
        const int fbid = blockIdx.x;
        int m = (int)(32.0f - sqrtf((float)(1024 - fbid)));
        while ((m + 1) * (63 - m) <= fbid) ++m;
        while (m * (64 - m) > fbid) --m;
        int rem = fbid - m * (64 - m);
        int h = 32 - m;                               // full chunks of I=2m
        I = 2 * m + (rem >= h ? 1 : 0);
        c = rem - (rem >= h ? h : 0);
        ngrp2 = 2;
    } else {
        const int hbid = blockIdx.x - 1024;           // half chunks: odd I, J0=63
        I = 2 * hbid + 1;
        c = 31 - hbid;
        ngrp2 = 1;
    }
    const int J0  = I + 2 * c;
    const int wr0 = I * GRP + wv * 32;

    const __bf16* zn = (const __bf16*)zn_;

    // A fragments: rows wr0 + g*16 + l15 (g=0,1), k-slice s: k = s*32 + lb*8..+7
    bf16x8 a_[2][4];
    #pragma unroll
    for (int g = 0; g < 2; ++g) {
        const __bf16* p = zn + (size_t)(wr0 + g * 16 + l15) * DIM + lb * 8;
        #pragma unroll
        for (int s = 0; s < 4; ++s)
            a_[g][s] = *(const bf16x8*)(p + s * 32);
    }

    // staging: 1024 granules of 16B per tile; 256 threads -> 4 each.
    // LDS granule (col, slot) at col*256+slot*16 holds global k-chunk slot^(col&7)
    const char* gB = (const char*)(zn + (size_t)J0 * GRP * DIM);
    int srcoff[4];
    #pragma unroll
    for (int i = 0; i < 4; ++i) {
        int m2 = (wv * 4 + i) * 64 + lane;
        int col = m2 >> 4, slot = m2 & 15;
        srcoff[i] = col * 256 + (slot ^ (col & 7)) * 16;
    }

    auto STAGE = [&](int t) {
        const char* src = gB + (size_t)t * (TILE_C * 256);
        #pragma unroll
        for (int i = 0; i < 4; ++i)                   // LDS dest: uniform + lane*16
            gll16(src + srcoff[i], Bs[t & 1] + (wv * 4 + i) * 1024);
    };

    f32x4 sumexp[2] = {};                             // row-direction sums
    float csr[16] = {};                               // col-direction partials

    auto CMP = [&](auto tc) {
        constexpr int t = tc.value;
        const char* buf = Bs[t & 1];
        const int c0t = J0 * GRP + t * TILE_C;
        const int Jg  = J0 + (t >> 1);
        const bool diagtile = ((unsigned)(wr0 - c0t) < (unsigned)TILE_C); // wave-uniform
        const bool docol    = (Jg != I);
        #pragma unroll
        for (int cb = 0; cb < 4; ++cb) {
            const int cc = cb * 16 + l15;             // local col in tile
            const char* pc = buf + cc * 256;
            bf16x8 b[4];
            #pragma unroll
            for (int s = 0; s < 4; ++s)
                b[s] = *(const bf16x8*)(pc + ((lb + s * 4) ^ (cc & 7)) * 16);
            f32x4 acc[2] = {};
            #pragma unroll
            for (int g = 0; g < 2; ++g)
                #pragma unroll
                for (int s = 0; s < 4; ++s)
                    acc[g] = __builtin_amdgcn_mfma_f32_16x16x32_bf16(a_[g][s], b[s], acc[g], 0, 0, 0);
            // C layout: col = c0t+cc, row = wr0+g*16+lb*4+v
            const int mycol = c0t + cc;
            if (diagtile) {                           // implies Jg==I (no colsum)
                #pragma unroll
                for (int g = 0; g < 2; ++g)
                    #pragma unroll
                    for (int v = 0; v < 4; ++v) {
                        float e = __builtin_amdgcn_exp2f(acc[g][v] * C_LOG2E2);
                        int row = wr0 + g * 16 + lb * 4 + v;
                        sumexp[g][v] += (mycol == row) ? 0.0f : e;   // exclude self
                    }
            } else {
                float cs = 0.0f;
                #pragma unroll
                for (int g = 0; g < 2; ++g)
                    #pragma unroll
                    for (int v = 0; v < 4; ++v) {
                        float e = __builtin_amdgcn_exp2f(acc[g][v] * C_LOG2E2);
                        sumexp[g][v] += e;
                        cs += e;
                    }
                if (docol) csr[t * 4 + cb] += cs;     // static index
            }
        }
    };

    // pipeline: full chunk = 4 tiles ping-pong; half chunk = 2 tiles up front
    STAGE(0);
    if (ngrp2 == 2) {
        __syncthreads(); STAGE(1);
        CMP(std::integral_constant<int, 0>{}); __syncthreads(); STAGE(2);
        CMP(std::integral_constant<int, 1>{}); __syncthreads(); STAGE(3);
        CMP(std::integral_constant<int, 2>{}); __syncthreads();
        CMP(std::integral_constant<int, 3>{});
    } else {
        STAGE(1); __syncthreads();
        CMP(std::integral_constant<int, 0>{});
        CMP(std::integral_constant<int, 1>{});
    }

    // row-direction: reduce across the 16 lanes (cols) sharing each row
    #pragma unroll
    for (int m = 1; m <= 8; m <<= 1)
        #pragma unroll
        for (int g = 0; g < 2; ++g)
            #pragma unroll
            for (int v = 0; v < 4; ++v)
                sumexp[g][v] += __shfl_xor(sumexp[g][v], m);

    if (l15 == 0) {
        #pragma unroll
        for (int g = 0; g < 2; ++g) {
            int row = wr0 + g * 16 + lb * 4;
            *(f32x4*)&S_contrib[(size_t)c * N_TOT + row] = sumexp[g];
        }
    }

    // col-direction: reduce lb groups, combine 4 waves via LDS, write slot 32+I
    #pragma unroll
    for (int k = 0; k < 16; ++k) {
        float v = csr[k];
        v += __shfl_xor(v, 16);
        v += __shfl_xor(v, 32);
        if (lb == 0) colred[wv][k * 16 + l15] = v;    // strip col k*16+l15
    }
    __syncthreads();
    if (tid < GRP * ngrp2) {
        int Jg = J0 + (tid >> 7);
        if (Jg != I) {
            float s = colred[0][tid] + colred[1][tid] + colred[2][tid] + colred[3][tid];
            S_contrib[(size_t)(32 + I) * N_TOT + J0 * GRP + tid] = s;
        }
    }
}

// bf16-pair dot helper (uint = 2 packed bf16)
__device__ inline float bdot(unsigned a, unsigned b) {
    float alo = __uint_as_float(a << 16), ahi = __uint_as_float(a & 0xffff0000u);
    float blo = __uint_as_float(b << 16), bhi = __uint_as_float(b & 0xffff0000u);
    return fmaf(alo, blo, ahi * bhi);
}

// ---------------- kernel 3: per-row loss over valid slots ----------------
// Row r in group G: rowsum slots 0..nch(G)-1, colsum slots 32..31+G.
__global__ __launch_bounds__(128) void k_rowsum(const float* __restrict__ S_contrib,
                                                const __hip_bfloat16* __restrict__ zn_,
                                                float* __restrict__ blk_out) {
    const int G = blockIdx.x;                         // 64 groups
    const int r = G * GRP + threadIdx.x;              // 128 threads
    const int nch = (65 - G) >> 1;

    float S = 0.0f;
    for (int s = 0; s < nch; ++s)      S += S_contrib[(size_t)s * N_TOT + r];
    for (int s = 32; s < 32 + G; ++s)  S += S_contrib[(size_t)s * N_TOT + r];

    const uint4* pa = (const uint4*)((const __bf16*)zn_ + (size_t)r * DIM);
    const uint4* pb = (const uint4*)((const __bf16*)zn_ + (size_t)(r ^ BATCH) * DIM);
    float dot = 0.0f;
    #pragma unroll
    for (int cc = 0; cc < DIM / 8; ++cc) {
        uint4 ua = pa[cc], ub = pb[cc];
        dot += bdot(ua.x, ub.x) + bdot(ua.y, ub.y) + bdot(ua.z, ub.z) + bdot(ua.w, ub.w);
    }

    float contrib = __logf(S) - 2.0f * dot;

    #pragma unroll
    for (int m = 1; m < 64; m <<= 1) contrib += __shfl_xor(contrib, m);
    __shared__ float sm[2];
    if ((threadIdx.x & 63) == 0) sm[threadIdx.x >> 6] = contrib;
    __syncthreads();
    if (threadIdx.x == 0) blk_out[G] = sm[0] + sm[1];
}

// ---------------- kernel 4: final scalar ----------------
__global__ void k_final(const float* __restrict__ blk_out, float* __restrict__ out) {
    float v = blk_out[threadIdx.x];                   // 64 threads, 64 groups
    #pragma unroll
    for (int m = 1; m < 64; m <<= 1) v += __shfl_xor(v, m);
    if (threadIdx.x == 0) out[0] = v / (float)N_TOT;
}

extern "C" void kernel_launch(void* const* d_in, const int* in_sizes, int n_in,
                              void* d_out, int out_size, void* d_ws, size_t ws_size,
                              hipStream_t stream) {
    const float* zi = (const float*)d_in[0];
    const float* zj = (const float*)d_in[1];
    char* ws = (char*)d_ws;
    __hip_bfloat16* zn = (__hip_bfloat16*)ws;                        // 2 MB
    float* S_contrib = (float*)(ws + (size_t)2 * 1024 * 1024);       // 3 MB (96 slots)
    float* blk       = (float*)(ws + (size_t)5 * 1024 * 1024 + 65536);
    float* out       = (float*)d_out;

    k_normalize<<<N_TOT / 4, 256, 0, stream>>>(zi, zj, zn);
    k_main<<<NBLK, 256, 0, stream>>>(zn, S_contrib);
    k_rowsum<<<NGRP, 128, 0, stream>>>(S_contrib, zn, blk);
    k_final<<<1, 64, 0, stream>>>(blk, out);
}

// Round 9
// 48.393 us; speedup vs baseline: 1.3822x; 1.3822x over previous
//
#include <hip/hip_runtime.h>
#include <hip/hip_bf16.h>

// SimCLR loss, MI355X. N=8192 rows, D=128, T=0.5.
// normalize(f32->bf16) -> SYMMETRIC sim-GEMM + sum(exp(2*dot)) over the
// 128-row-group upper triangle, blocks = (I, chunk of 2 J-groups), NT=4
// pipelined 64-col LDS tiles. 1024 full chunks dispatch first (balanced),
// 32 half-chunks trail. Fixed-max logsumexp (|sim|<=2) -> no online max.
// R9: launch_bounds(256,3) (the non-spilling regime: (256,4) binaries came
// back 64-reg + 42MB scratch traffic in R4/R8) and colsum partials flushed
// to LDS per-tile (kills the 16-reg csr array; single write, no RMW).

#define BATCH 4096
#define N_TOT 8192
#define DIM 128
#define GRP 128                           // rows per group
#define NGRP 64
#define TILE_C 64                         // cols per LDS B-tile (16 KB)
#define NBLK 1056                         // 1024 full + 32 half chunks

// exp(2d) == exp2(d * 2/ln2)
#define C_LOG2E2 2.8853900817779268f

using bf16x8 = __attribute__((ext_vector_type(8))) __bf16;
using f32x4  = __attribute__((ext_vector_type(4))) float;

typedef __attribute__((address_space(1))) const void cg_void;
typedef __attribute__((address_space(3))) void lds_void;
__device__ __forceinline__ void gll16(const void* g, void* l) {
    __builtin_amdgcn_global_load_lds((cg_void*)g, (lds_void*)l, 16, 0, 0);
}

// ---------------- kernel 1: normalize rows, write bf16 ----------------
__global__ __launch_bounds__(256) void k_normalize(const float* __restrict__ zi,
                                                   const float* __restrict__ zj,
                                                   __hip_bfloat16* __restrict__ zn) {
    int row  = blockIdx.x * 4 + (threadIdx.x >> 6);
    int lane = threadIdx.x & 63;
    const float* src = (row < BATCH) ? (zi + (size_t)row * DIM)
                                     : (zj + (size_t)(row - BATCH) * DIM);
    float2 v = ((const float2*)src)[lane];
    float ss = v.x * v.x + v.y * v.y;
    #pragma unroll
    for (int m = 1; m < 64; m <<= 1) ss += __shfl_xor(ss, m);
    float inv = 1.0f / fmaxf(sqrtf(ss), 1e-8f);
    __hip_bfloat162 o;
    o.x = __float2bfloat16(v.x * inv);
    o.y = __float2bfloat16(v.y * inv);
    ((__hip_bfloat162*)(zn + (size_t)row * DIM))[lane] = o;
}

// ---------------- kernel 2: symmetric sim GEMM + exp row/col sums ----------------
// Block (I, chunk c): A = 128 rows of group I in regs (32/wave), B = cols of
// groups J0=I+2c, J0+1 (full) or J0=63 (half), 64-col XOR-swizzled LDS tiles,
// ping-pong, stage(t+1) under compute(t). Rowsum(rows I) -> slot c;
// colsum(rows Jg) -> slot 32+I. One writer per (slot,row): deterministic.
__global__ __launch_bounds__(256, 3) void k_main(const __hip_bfloat16* __restrict__ zn_,
                                                 float* __restrict__ S_contrib) {
    __shared__ __align__(16) char Bs[2][TILE_C * 256];       // 32 KB
    __shared__ float colred[4][256];                         // 4 KB

    const int tid  = threadIdx.x;
    const int lane = tid & 63;
    const int wv   = tid >> 6;                        // 0..3
    const int l15  = lane & 15;
    const int lb   = lane >> 4;                       // 0..3

    // decode block -> (I, c): full chunks first (F(m) = m*(64-m) per I-pair)
    int I, c, ngrp2;
    if (blockIdx.x < 1024) {
        const int fbid = blockIdx.x;
        int m = (int)(32.0f - sqrtf((float)(1024 - fbid)));
        while ((m + 1) * (63 - m) <= fbid) ++m;
        while (m * (64 - m) > fbid) --m;
        int rem = fbid - m * (64 - m);
        int h = 32 - m;                               // full chunks of I=2m
        I = 2 * m + (rem >= h ? 1 : 0);
        c = rem - (rem >= h ? h : 0);
        ngrp2 = 2;
    } else {
        const int hbid = blockIdx.x - 1024;           // half chunks: odd I, J0=63
        I = 2 * hbid + 1;
        c = 31 - hbid;
        ngrp2 = 1;
    }
    const int J0  = I + 2 * c;
    const int wr0 = I * GRP + wv * 32;

    const __bf16* zn = (const __bf16*)zn_;

    // A fragments: rows wr0 + g*16 + l15 (g=0,1), k-slice s: k = s*32 + lb*8..+7
    bf16x8 a_[2][4];
    #pragma unroll
    for (int g = 0; g < 2; ++g) {
        const __bf16* p = zn + (size_t)(wr0 + g * 16 + l15) * DIM + lb * 8;
        #pragma unroll
        for (int s = 0; s < 4; ++s)
            a_[g][s] = *(const bf16x8*)(p + s * 32);
    }

    // staging: 1024 granules of 16B per tile; 256 threads -> 4 each.
    // LDS granule (col, slot) at col*256+slot*16 holds global k-chunk slot^(col&7)
    const char* gB = (const char*)(zn + (size_t)J0 * GRP * DIM);
    int srcoff[4];
    #pragma unroll
    for (int i = 0; i < 4; ++i) {
        int m2 = (wv * 4 + i) * 64 + lane;
        int col = m2 >> 4, slot = m2 & 15;
        srcoff[i] = col * 256 + (slot ^ (col & 7)) * 16;
    }

    auto STAGE = [&](int t) {
        const char* src = gB + (size_t)t * (TILE_C * 256);
        #pragma unroll
        for (int i = 0; i < 4; ++i)                   // LDS dest: uniform + lane*16
            gll16(src + srcoff[i], Bs[t & 1] + (wv * 4 + i) * 1024);
    };

    f32x4 sumexp[2] = {};                             // row-direction sums

    auto CMP = [&](int t) {
        const char* buf = Bs[t & 1];
        const int c0t = J0 * GRP + t * TILE_C;
        const int Jg  = J0 + (t >> 1);
        const bool diagtile = ((unsigned)(wr0 - c0t) < (unsigned)TILE_C); // wave-uniform
        const bool docol    = (Jg != I);              // wave-uniform
        float csr4[4];                                // this tile's colsum partials
        #pragma unroll
        for (int cb = 0; cb < 4; ++cb) {
            const int cc = cb * 16 + l15;             // local col in tile
            const char* pc = buf + cc * 256;
            bf16x8 b[4];
            #pragma unroll
            for (int s = 0; s < 4; ++s)
                b[s] = *(const bf16x8*)(pc + ((lb + s * 4) ^ (cc & 7)) * 16);
            f32x4 acc[2] = {};
            #pragma unroll
            for (int g = 0; g < 2; ++g)
                #pragma unroll
                for (int s = 0; s < 4; ++s)
                    acc[g] = __builtin_amdgcn_mfma_f32_16x16x32_bf16(a_[g][s], b[s], acc[g], 0, 0, 0);
            // C layout: col = c0t+cc, row = wr0+g*16+lb*4+v
            const int mycol = c0t + cc;
            if (diagtile) {                           // implies Jg==I (no colsum)
                #pragma unroll
                for (int g = 0; g < 2; ++g)
                    #pragma unroll
                    for (int v = 0; v < 4; ++v) {
                        float e = __builtin_amdgcn_exp2f(acc[g][v] * C_LOG2E2);
                        int row = wr0 + g * 16 + lb * 4 + v;
                        sumexp[g][v] += (mycol == row) ? 0.0f : e;   // exclude self
                    }
                csr4[cb] = 0.0f;
            } else {
                float cs = 0.0f;
                #pragma unroll
                for (int g = 0; g < 2; ++g)
                    #pragma unroll
                    for (int v = 0; v < 4; ++v) {
                        float e = __builtin_amdgcn_exp2f(acc[g][v] * C_LOG2E2);
                        sumexp[g][v] += e;
                        cs += e;
                    }
                csr4[cb] = cs;
            }
        }
        // colsum flush for this tile: written exactly once per (wv, col)
        if (docol) {
            #pragma unroll
            for (int cb = 0; cb < 4; ++cb) {
                float v = csr4[cb];
                v += __shfl_xor(v, 16);
                v += __shfl_xor(v, 32);
                if (lb == 0) colred[wv][t * TILE_C + cb * 16 + l15] = v;
            }
        }
    };

    // pipeline: full chunk = 4 tiles ping-pong; half chunk = 2 tiles up front
    STAGE(0);
    if (ngrp2 == 2) {
        __syncthreads(); STAGE(1);
        CMP(0); __syncthreads(); STAGE(2);
        CMP(1); __syncthreads(); STAGE(3);
        CMP(2); __syncthreads();
        CMP(3);
    } else {
        STAGE(1); __syncthreads();
        CMP(0);
        CMP(1);
    }

    // row-direction: reduce across the 16 lanes (cols) sharing each row
    #pragma unroll
    for (int m = 1; m <= 8; m <<= 1)
        #pragma unroll
        for (int g = 0; g < 2; ++g)
            #pragma unroll
            for (int v = 0; v < 4; ++v)
                sumexp[g][v] += __shfl_xor(sumexp[g][v], m);

    if (l15 == 0) {
        #pragma unroll
        for (int g = 0; g < 2; ++g) {
            int row = wr0 + g * 16 + lb * 4;
            *(f32x4*)&S_contrib[(size_t)c * N_TOT + row] = sumexp[g];
        }
    }

    // col-direction: combine the 4 waves' partials, write slot 32+I
    __syncthreads();
    if (tid < GRP * ngrp2) {
        int Jg = J0 + (tid >> 7);
        if (Jg != I) {
            float s = colred[0][tid] + colred[1][tid] + colred[2][tid] + colred[3][tid];
            S_contrib[(size_t)(32 + I) * N_TOT + J0 * GRP + tid] = s;
        }
    }
}

// bf16-pair dot helper (uint = 2 packed bf16)
__device__ inline float bdot(unsigned a, unsigned b) {
    float alo = __uint_as_float(a << 16), ahi = __uint_as_float(a & 0xffff0000u);
    float blo = __uint_as_float(b << 16), bhi = __uint_as_float(b & 0xffff0000u);
    return fmaf(alo, blo, ahi * bhi);
}

// ---------------- kernel 3: per-row loss over valid slots ----------------
// Row r in group G: rowsum slots 0..nch(G)-1, colsum slots 32..31+G.
__global__ __launch_bounds__(128) void k_rowsum(const float* __restrict__ S_contrib,
                                                const __hip_bfloat16* __restrict__ zn_,
                                                float* __restrict__ blk_out) {
    const int G = blockIdx.x;                         // 64 groups
    const int r = G * GRP + threadIdx.x;              // 128 threads
    const int nch = (65 - G) >> 1;

    float S = 0.0f;
    for (int s = 0; s < nch; ++s)      S += S_contrib[(size_t)s * N_TOT + r];
    for (int s = 32; s < 32 + G; ++s)  S += S_contrib[(size_t)s * N_TOT + r];

    const uint4* pa = (const uint4*)((const __bf16*)zn_ + (size_t)r * DIM);
    const uint4* pb = (const uint4*)((const __bf16*)zn_ + (size_t)(r ^ BATCH) * DIM);
    float dot = 0.0f;
    #pragma unroll
    for (int cc = 0; cc < DIM / 8; ++cc) {
        uint4 ua = pa[cc], ub = pb[cc];
        dot += bdot(ua.x, ub.x) + bdot(ua.y, ub.y) + bdot(ua.z, ub.z) + bdot(ua.w, ub.w);
    }

    float contrib = __logf(S) - 2.0f * dot;

    #pragma unroll
    for (int m = 1; m < 64; m <<= 1) contrib += __shfl_xor(contrib, m);
    __shared__ float sm[2];
    if ((threadIdx.x & 63) == 0) sm[threadIdx.x >> 6] = contrib;
    __syncthreads();
    if (threadIdx.x == 0) blk_out[G] = sm[0] + sm[1];
}

// ---------------- kernel 4: final scalar ----------------
__global__ void k_final(const float* __restrict__ blk_out, float* __restrict__ out) {
    float v = blk_out[threadIdx.x];                   // 64 threads, 64 groups
    #pragma unroll
    for (int m = 1; m < 64; m <<= 1) v += __shfl_xor(v, m);
    if (threadIdx.x == 0) out[0] = v / (float)N_TOT;
}

extern "C" void kernel_launch(void* const* d_in, const int* in_sizes, int n_in,
                              void* d_out, int out_size, void* d_ws, size_t ws_size,
                              hipStream_t stream) {
    const float* zi = (const float*)d_in[0];
    const float* zj = (const float*)d_in[1];
    char* ws = (char*)d_ws;
    __hip_bfloat16* zn = (__hip_bfloat16*)ws;                        // 2 MB
    float* S_contrib = (float*)(ws + (size_t)2 * 1024 * 1024);       // 3 MB (96 slots)
    float* blk       = (float*)(ws + (size_t)5 * 1024 * 1024 + 65536);
    float* out       = (float*)d_out;

    k_normalize<<<N_TOT / 4, 256, 0, stream>>>(zi, zj, zn);
    k_main<<<NBLK, 256, 0, stream>>>(zn, S_contrib);
    k_rowsum<<<NGRP, 128, 0, stream>>>(S_contrib, zn, blk);
    k_final<<<1, 64, 0, stream>>>(blk, out);
}

// Round 10
// 37.165 us; speedup vs baseline: 1.7998x; 1.3021x over previous
//
#include <hip/hip_runtime.h>
#include <hip/hip_bf16.h>

// SimCLR loss, MI355X. N=8192 rows, D=128, T=0.5.
// normalize(f32->bf16) -> SYMMETRIC sim-GEMM + sum(exp(2*dot)) over the
// 128x128 upper-triangle tasks (2080 blocks, one task each; 8.1 tasks/CU ->
// fine-grained balance). Per task: A (128 rows of I) in regs, B (128 cols of
// J) staged to LDS up front, ONE barrier, straight-line 2-tile compute;
// rowsum -> slot J of group I, colsum -> slot I of group J (dense 64-slot
// packing, single writer per entry). Fixed-max logsumexp (|sim|<=2).

#define BATCH 4096
#define N_TOT 8192
#define DIM 128
#define GRP 128
#define NGRP 64
#define TILE_C 64                         // cols per LDS B-tile (16 KB)
#define NTASK 2080                        // 64*65/2

// exp(2d) == exp2(d * 2/ln2)
#define C_LOG2E2 2.8853900817779268f

using bf16x8 = __attribute__((ext_vector_type(8))) __bf16;
using f32x4  = __attribute__((ext_vector_type(4))) float;

typedef __attribute__((address_space(1))) const void cg_void;
typedef __attribute__((address_space(3))) void lds_void;
__device__ __forceinline__ void gll16(const void* g, void* l) {
    __builtin_amdgcn_global_load_lds((cg_void*)g, (lds_void*)l, 16, 0, 0);
}

// ---------------- kernel 1: normalize rows, write bf16 ----------------
__global__ __launch_bounds__(256) void k_normalize(const float* __restrict__ zi,
                                                   const float* __restrict__ zj,
                                                   __hip_bfloat16* __restrict__ zn) {
    int row  = blockIdx.x * 4 + (threadIdx.x >> 6);
    int lane = threadIdx.x & 63;
    const float* src = (row < BATCH) ? (zi + (size_t)row * DIM)
                                     : (zj + (size_t)(row - BATCH) * DIM);
    float2 v = ((const float2*)src)[lane];
    float ss = v.x * v.x + v.y * v.y;
    #pragma unroll
    for (int m = 1; m < 64; m <<= 1) ss += __shfl_xor(ss, m);
    float inv = 1.0f / fmaxf(sqrtf(ss), 1e-8f);
    __hip_bfloat162 o;
    o.x = __float2bfloat16(v.x * inv);
    o.y = __float2bfloat16(v.y * inv);
    ((__hip_bfloat162*)(zn + (size_t)row * DIM))[lane] = o;
}

// ---------------- kernel 2: one 128x128 triangle task per block ----------------
__global__ __launch_bounds__(256, 3) void k_main(const __hip_bfloat16* __restrict__ zn_,
                                                 float* __restrict__ S_contrib) {
    __shared__ __align__(16) char Bs[2][TILE_C * 256];       // 32 KB
    __shared__ float colred[4][GRP];                         // 2 KB

    const int tid  = threadIdx.x;
    const int lane = tid & 63;
    const int wv   = tid >> 6;                        // 0..3
    const int l15  = lane & 15;
    const int lb   = lane >> 4;                       // 0..3

    // O(1) triangle decode: base(I) = 64*I - I*(I-1)/2, row length 64-I
    const int idx = blockIdx.x;
    int I = (int)(64.5f - sqrtf(64.5f * 64.5f - 2.0f * (float)idx));
    int base = 64 * I - ((I * (I - 1)) >> 1);
    if (idx < base)                 { --I; base = 64 * I - ((I * (I - 1)) >> 1); }
    else if (idx >= base + 64 - I)  { ++I; base = 64 * I - ((I * (I - 1)) >> 1); }
    const int J = I + (idx - base);
    const bool isdiag = (I == J);

    const int wr0 = I * GRP + wv * 32;

    const __bf16* zn = (const __bf16*)zn_;

    // A fragments: rows wr0 + g*16 + l15 (g=0,1), k-slice s: k = s*32 + lb*8..+7
    bf16x8 a_[2][4];
    #pragma unroll
    for (int g = 0; g < 2; ++g) {
        const __bf16* p = zn + (size_t)(wr0 + g * 16 + l15) * DIM + lb * 8;
        #pragma unroll
        for (int s = 0; s < 4; ++s)
            a_[g][s] = *(const bf16x8*)(p + s * 32);
    }

    // stage BOTH 64-col tiles up front (8 gll16/thread). LDS granule
    // (col, slot) at col*256+slot*16 holds global k-chunk slot^(col&7)
    // (linear LDS dest + inverse-swizzled global src, rule #21).
    const char* gB = (const char*)(zn + (size_t)J * GRP * DIM);
    {
        int srcoff[4];
        #pragma unroll
        for (int i = 0; i < 4; ++i) {
            int m2 = (wv * 4 + i) * 64 + lane;
            int col = m2 >> 4, slot = m2 & 15;
            srcoff[i] = col * 256 + (slot ^ (col & 7)) * 16;
        }
        #pragma unroll
        for (int t = 0; t < 2; ++t) {
            const char* src = gB + (size_t)t * (TILE_C * 256);
            #pragma unroll
            for (int i = 0; i < 4; ++i)               // dest: uniform + lane*16
                gll16(src + srcoff[i], Bs[t] + (wv * 4 + i) * 1024);
        }
    }

    f32x4 sumexp[2] = {};                             // row-direction sums

    __syncthreads();                                  // drains gll16 (vmcnt 0)

    auto CMP = [&](int t) {
        const char* buf = Bs[t];
        const int c0t = J * GRP + t * TILE_C;
        const bool diagtile = ((unsigned)(wr0 - c0t) < (unsigned)TILE_C); // wave-uniform
        float csr4[4];
        #pragma unroll
        for (int cb = 0; cb < 4; ++cb) {
            const int cc = cb * 16 + l15;             // local col in tile
            const char* pc = buf + cc * 256;
            bf16x8 b[4];
            #pragma unroll
            for (int s = 0; s < 4; ++s)
                b[s] = *(const bf16x8*)(pc + ((lb + s * 4) ^ (cc & 7)) * 16);
            f32x4 acc[2] = {};
            #pragma unroll
            for (int g = 0; g < 2; ++g)
                #pragma unroll
                for (int s = 0; s < 4; ++s)
                    acc[g] = __builtin_amdgcn_mfma_f32_16x16x32_bf16(a_[g][s], b[s], acc[g], 0, 0, 0);
            // C layout: col = c0t+cc, row = wr0+g*16+lb*4+v
            const int mycol = c0t + cc;
            if (diagtile) {                           // only inside diag blocks
                #pragma unroll
                for (int g = 0; g < 2; ++g)
                    #pragma unroll
                    for (int v = 0; v < 4; ++v) {
                        float e = __builtin_amdgcn_exp2f(acc[g][v] * C_LOG2E2);
                        int row = wr0 + g * 16 + lb * 4 + v;
                        sumexp[g][v] += (mycol == row) ? 0.0f : e;   // exclude self
                    }
                csr4[cb] = 0.0f;
            } else {
                float cs = 0.0f;
                #pragma unroll
                for (int g = 0; g < 2; ++g)
                    #pragma unroll
                    for (int v = 0; v < 4; ++v) {
                        float e = __builtin_amdgcn_exp2f(acc[g][v] * C_LOG2E2);
                        sumexp[g][v] += e;
                        cs += e;
                    }
                csr4[cb] = cs;
            }
        }
        if (!isdiag) {                                // flush tile's colsums
            #pragma unroll
            for (int cb = 0; cb < 4; ++cb) {
                float v = csr4[cb];
                v += __shfl_xor(v, 16);
                v += __shfl_xor(v, 32);
                if (lb == 0) colred[wv][t * TILE_C + cb * 16 + l15] = v;
            }
        }
    };

    CMP(0);
    CMP(1);

    // row-direction: reduce across the 16 lanes (cols) sharing each row,
    // write slot J for rows of group I
    #pragma unroll
    for (int m = 1; m <= 8; m <<= 1)
        #pragma unroll
        for (int g = 0; g < 2; ++g)
            #pragma unroll
            for (int v = 0; v < 4; ++v)
                sumexp[g][v] += __shfl_xor(sumexp[g][v], m);

    if (l15 == 0) {
        #pragma unroll
        for (int g = 0; g < 2; ++g) {
            int row = wr0 + g * 16 + lb * 4;
            *(f32x4*)&S_contrib[(size_t)J * N_TOT + row] = sumexp[g];
        }
    }

    // col-direction: combine 4 waves, write slot I for rows of group J
    if (!isdiag) {
        __syncthreads();
        if (tid < GRP) {
            float s = colred[0][tid] + colred[1][tid] + colred[2][tid] + colred[3][tid];
            S_contrib[(size_t)I * N_TOT + J * GRP + tid] = s;
        }
    }
}

// bf16-pair dot helper (uint = 2 packed bf16)
__device__ inline float bdot(unsigned a, unsigned b) {
    float alo = __uint_as_float(a << 16), ahi = __uint_as_float(a & 0xffff0000u);
    float blo = __uint_as_float(b << 16), bhi = __uint_as_float(b & 0xffff0000u);
    return fmaf(alo, blo, ahi * bhi);
}

// ---------------- kernel 3: per-row loss (all 64 slots valid) ----------------
__global__ __launch_bounds__(256) void k_rowsum(const float* __restrict__ S_contrib,
                                                const __hip_bfloat16* __restrict__ zn_,
                                                float* __restrict__ blk_out) {
    const int r = blockIdx.x * 256 + threadIdx.x;
    float S = 0.0f;
    #pragma unroll
    for (int s = 0; s < NGRP; ++s) S += S_contrib[(size_t)s * N_TOT + r];

    const uint4* pa = (const uint4*)((const __bf16*)zn_ + (size_t)r * DIM);
    const uint4* pb = (const uint4*)((const __bf16*)zn_ + (size_t)(r ^ BATCH) * DIM);
    float dot = 0.0f;
    #pragma unroll
    for (int cc = 0; cc < DIM / 8; ++cc) {
        uint4 ua = pa[cc], ub = pb[cc];
        dot += bdot(ua.x, ub.x) + bdot(ua.y, ub.y) + bdot(ua.z, ub.z) + bdot(ua.w, ub.w);
    }

    float contrib = __logf(S) - 2.0f * dot;

    #pragma unroll
    for (int m = 1; m < 64; m <<= 1) contrib += __shfl_xor(contrib, m);
    __shared__ float sm[4];
    if ((threadIdx.x & 63) == 0) sm[threadIdx.x >> 6] = contrib;
    __syncthreads();
    if (threadIdx.x == 0) blk_out[blockIdx.x] = sm[0] + sm[1] + sm[2] + sm[3];
}

// ---------------- kernel 4: final scalar ----------------
__global__ void k_final(const float* __restrict__ blk_out, float* __restrict__ out) {
    float v = (threadIdx.x < 32) ? blk_out[threadIdx.x] : 0.0f;
    #pragma unroll
    for (int m = 1; m < 64; m <<= 1) v += __shfl_xor(v, m);
    if (threadIdx.x == 0) out[0] = v / (float)N_TOT;
}

extern "C" void kernel_launch(void* const* d_in, const int* in_sizes, int n_in,
                              void* d_out, int out_size, void* d_ws, size_t ws_size,
                              hipStream_t stream) {
    const float* zi = (const float*)d_in[0];
    const float* zj = (const float*)d_in[1];
    char* ws = (char*)d_ws;
    __hip_bfloat16* zn = (__hip_bfloat16*)ws;                        // 2 MB
    float* S_contrib = (float*)(ws + (size_t)2 * 1024 * 1024);       // 2 MB (64 slots)
    float* blk       = (float*)(ws + (size_t)4 * 1024 * 1024);       // 128 B
    float* out       = (float*)d_out;

    k_normalize<<<N_TOT / 4, 256, 0, stream>>>(zi, zj, zn);
    k_main<<<NTASK, 256, 0, stream>>>(zn, S_contrib);
    k_rowsum<<<N_TOT / 256, 256, 0, stream>>>(S_contrib, zn, blk);
    k_final<<<1, 64, 0, stream>>>(blk, out);
}